// Round 5
// baseline (176.966 us; speedup 1.0000x reference)
//
#include <hip/hip_runtime.h>

#define N_GENE 4762
#define N_CELL 847
#define NEDGE  200000
#define D      256
#define NPART  64     // partial-histogram blocks (also scatter blocks)

typedef __attribute__((ext_vector_type(8))) short short8;   // 8 bf16 (4 VGPRs)
typedef __attribute__((ext_vector_type(4))) float f32x4;

// ---- histogram segment layout (bins, concatenated) ----
#define S_G_OUT 0                      // [4762] g2c_src degrees (genes)
#define S_C_IN  (S_G_OUT + N_GENE)     // [847]  g2c_dst degrees (cells)
#define S_C_OUT (S_C_IN + N_CELL)      // [847]  c2g_src degrees (cells)
#define S_G_IN  (S_C_OUT + N_CELL)     // [4762] c2g_dst degrees (genes)
#define NBINS   (S_G_IN + N_GENE)      // 11218

// ---- workspace layout (4-byte slots) ----
#define A_DEG      0                        // int[11218]
#define A_NRM      NBINS                    // float[11218]
#define A_OFFS_C   (A_NRM + NBINS)          // int[848]
#define A_OFFS_G   (A_OFFS_C + N_CELL + 1)  // int[4763]
#define A_SORT_C   (A_OFFS_G + N_GENE + 1)  // int[200000]
#define A_SORT_G   (A_SORT_C + NEDGE)       // int[200000]
#define A_PART     (A_SORT_G + NEDGE)       // int[64*11218]
#define A_SG       (A_PART + NPART * NBINS) // float[4762]
#define A_SC       (A_SG + N_GENE)          // float[847]
// bf16 regions (ushort counts; slot count = count/2)
#define A_GENE_BF  (A_SC + N_CELL)                  // ushort[4762*256]
#define A_CELL_BF  (A_GENE_BF + N_GENE * D / 2)     // ushort[847*256]
#define A_WT1_BF   (A_CELL_BF + N_CELL * D / 2)     // ushort[256*256] W_g2c^T
#define A_WT2_BF   (A_WT1_BF + D * D / 2)           // ushort[256*256] W_c2g^T
#define A_AGGC_BF  (A_WT2_BF + D * D / 2)           // ushort[847*256]
#define A_AGGG_BF  (A_AGGC_BF + N_CELL * D / 2)     // ushort[4762*256]

__device__ __forceinline__ unsigned short f2bf(float f) {
    unsigned u = __float_as_uint(f);
    u = (u + 0x7FFFu + ((u >> 16) & 1u)) >> 16;    // RNE
    return (unsigned short)u;
}
__device__ __forceinline__ float bf2f(unsigned short b) {
    return __uint_as_float(((unsigned)b) << 16);
}

// Convert embeddings to bf16; transpose W_g2c / W_c2g into Wt[n][k] bf16.
__global__ void k_cvt(const float* __restrict__ gene_emb,
                      const float* __restrict__ cell_emb,
                      const float* __restrict__ W_g2c,
                      const float* __restrict__ W_c2g,
                      unsigned short* __restrict__ gene_bf,
                      unsigned short* __restrict__ cell_bf,
                      unsigned short* __restrict__ wt1,
                      unsigned short* __restrict__ wt2) {
    const int NG = N_GENE * D, NC = N_CELL * D, NW = D * D;
    int i = blockIdx.x * blockDim.x + threadIdx.x;
    if (i < NG) {
        gene_bf[i] = f2bf(gene_emb[i]);
    } else if (i < NG + NC) {
        int j = i - NG;
        cell_bf[j] = f2bf(cell_emb[j]);
    } else if (i < NG + NC + NW) {
        int j = i - NG - NC;
        int n = j >> 8, k = j & 255;
        wt1[j] = f2bf(W_g2c[k * D + n]);
    } else if (i < NG + NC + 2 * NW) {
        int j = i - NG - NC - NW;
        int n = j >> 8, k = j & 255;
        wt2[j] = f2bf(W_c2g[k * D + n]);
    }
}

// Per-block LDS histograms of all 4 index arrays -> partial[b][j].
__global__ __launch_bounds__(1024) void k_hist_part(
        const int* __restrict__ g2c_src, const int* __restrict__ g2c_dst,
        const int* __restrict__ c2g_src, const int* __restrict__ c2g_dst,
        int* __restrict__ partial) {
    __shared__ int sh[NBINS];
    int tid = threadIdx.x;
    for (int j = tid; j < NBINS; j += 1024) sh[j] = 0;
    __syncthreads();
    const int chunk = (NEDGE + NPART - 1) / NPART;
    int e0 = blockIdx.x * chunk, e1 = min(NEDGE, e0 + chunk);
    for (int e = e0 + tid; e < e1; e += 1024) {
        atomicAdd(&sh[S_G_OUT + g2c_src[e]], 1);
        atomicAdd(&sh[S_C_IN  + g2c_dst[e]], 1);
        atomicAdd(&sh[S_C_OUT + c2g_src[e]], 1);
        atomicAdd(&sh[S_G_IN  + c2g_dst[e]], 1);
    }
    __syncthreads();
    int* p = partial + blockIdx.x * NBINS;
    for (int j = tid; j < NBINS; j += 1024) p[j] = sh[j];
}

// deg[j] = sum_b partial[b][j]; partial[b][j] := exclusive prefix over b;
// nrm[j] = rsqrt(max(deg,1)).
__global__ void k_hist_reduce(int* __restrict__ partial, int* __restrict__ deg,
                              float* __restrict__ nrm) {
    int j = blockIdx.x * blockDim.x + threadIdx.x;
    if (j < NBINS) {
        int s = 0;
        #pragma unroll 4
        for (int b = 0; b < NPART; b++) {
            int t = partial[b * NBINS + j];
            partial[b * NBINS + j] = s;
            s += t;
        }
        deg[j] = s;
        nrm[j] = rsqrtf(fmaxf((float)s, 1.0f));
    }
}

// Exclusive scan; block 0: cells (n=847), block 1: genes (n=4762).
__global__ __launch_bounds__(1024) void k_scan2(
        const int* __restrict__ degC, int* __restrict__ offsC,
        const int* __restrict__ degG, int* __restrict__ offsG) {
    const int* src = (blockIdx.x == 0) ? degC : degG;
    int* dst       = (blockIdx.x == 0) ? offsC : offsG;
    int n          = (blockIdx.x == 0) ? N_CELL : N_GENE;
    int tid = threadIdx.x;
    int per = (n + 1023) >> 10;
    int base = tid * per;
    int v[8];
    int s = 0;
    for (int i = 0; i < per; i++) {
        int x = (base + i < n) ? src[base + i] : 0;
        v[i] = s;
        s += x;
    }
    int lane = tid & 63, w = tid >> 6;
    int t = s;
    #pragma unroll
    for (int off = 1; off < 64; off <<= 1) {
        int u = __shfl_up(t, off);
        if (lane >= off) t += u;
    }
    __shared__ int wsum[16];
    if (lane == 63) wsum[w] = t;
    __syncthreads();
    if (w == 0 && lane < 16) {
        int x = wsum[lane];
        #pragma unroll
        for (int off = 1; off < 16; off <<= 1) {
            int u = __shfl_up(x, off);
            if (lane >= off) x += u;
        }
        wsum[lane] = x;
    }
    __syncthreads();
    int wbase = (w == 0) ? 0 : wsum[w - 1];
    int excl = wbase + t - s;
    for (int i = 0; i < per; i++)
        if (base + i < n) dst[base + i] = excl + v[i];
    if (tid == 1023) dst[n] = excl + s;
}

// Deterministic counting sort, zero global atomics. grid=(NPART, 2).
__global__ __launch_bounds__(1024) void k_scatter2(
        const int* __restrict__ g2c_src, const int* __restrict__ g2c_dst,
        const int* __restrict__ c2g_src, const int* __restrict__ c2g_dst,
        const int* __restrict__ partial,
        const int* __restrict__ offsC, const int* __restrict__ offsG,
        int* __restrict__ sortC, int* __restrict__ sortG) {
    __shared__ int sh[N_GENE];
    int tid = threadIdx.x;
    int dir = blockIdx.y;
    const int* src  = dir ? c2g_src : g2c_src;
    const int* dst  = dir ? c2g_dst : g2c_dst;
    const int* offs = dir ? offsG : offsC;
    int* sorted     = dir ? sortG : sortC;
    int seg         = dir ? S_G_IN : S_C_IN;
    int nb          = dir ? N_GENE : N_CELL;
    const int* base = partial + blockIdx.x * NBINS + seg;
    for (int j = tid; j < nb; j += 1024) sh[j] = base[j];
    __syncthreads();
    const int chunk = (NEDGE + NPART - 1) / NPART;
    int e0 = blockIdx.x * chunk, e1 = min(NEDGE, e0 + chunk);
    for (int e = e0 + tid; e < e1; e += 1024) {
        int d = dst[e];
        int r = atomicAdd(&sh[d], 1);
        sorted[offs[d] + r] = src[e];
    }
}

// Both directions fused; one wave per dst node, lane owns 4 columns.
// Gathers bf16 rows, accumulates f32, writes bf16 agg.
__global__ __launch_bounds__(256) void k_agg2(
        const unsigned short* __restrict__ gene_bf,
        const unsigned short* __restrict__ cell_bf,
        const int* __restrict__ sortC, const int* __restrict__ sortG,
        const int* __restrict__ offsC, const int* __restrict__ offsG,
        const float* __restrict__ nrm,
        unsigned short* __restrict__ aggC, unsigned short* __restrict__ aggG) {
    int w = threadIdx.x >> 6, lane = threadIdx.x & 63;
    int d = blockIdx.x * 4 + w;
    if (d >= N_CELL + N_GENE) return;
    bool isCell = d < N_CELL;
    int dd = isCell ? d : d - N_CELL;
    const unsigned short* emb = isCell ? gene_bf : cell_bf;
    const int*    sorted = isCell ? sortC : sortG;
    const int*    offs   = isCell ? offsC : offsG;
    const float*  nsrc   = isCell ? nrm + S_G_OUT : nrm + S_C_OUT;
    float         ndv    = isCell ? nrm[S_C_IN + dd] : nrm[S_G_IN + dd];
    unsigned short* agg  = isCell ? aggC : aggG;
    int e0 = offs[dd], e1 = offs[dd + 1];
    __shared__ int   sidx[4][64];
    __shared__ float snrm[4][64];
    float ax = 0.f, ay = 0.f, az = 0.f, aw = 0.f;
    for (int base = e0; base < e1; base += 64) {
        int n = min(64, e1 - base);
        if (lane < n) {
            int s = sorted[base + lane];
            sidx[w][lane] = s;
            snrm[w][lane] = nsrc[s];
        }
        // same-wave LDS write->read: program order, no barrier needed
        int i = 0;
        for (; i + 4 <= n; i += 4) {
            ushort4 v0 = *(const ushort4*)&emb[sidx[w][i + 0] * D + lane * 4];
            ushort4 v1 = *(const ushort4*)&emb[sidx[w][i + 1] * D + lane * 4];
            ushort4 v2 = *(const ushort4*)&emb[sidx[w][i + 2] * D + lane * 4];
            ushort4 v3 = *(const ushort4*)&emb[sidx[w][i + 3] * D + lane * 4];
            float n0 = snrm[w][i + 0], n1 = snrm[w][i + 1];
            float n2 = snrm[w][i + 2], n3 = snrm[w][i + 3];
            ax += bf2f(v0.x) * n0 + bf2f(v1.x) * n1 + bf2f(v2.x) * n2 + bf2f(v3.x) * n3;
            ay += bf2f(v0.y) * n0 + bf2f(v1.y) * n1 + bf2f(v2.y) * n2 + bf2f(v3.y) * n3;
            az += bf2f(v0.z) * n0 + bf2f(v1.z) * n1 + bf2f(v2.z) * n2 + bf2f(v3.z) * n3;
            aw += bf2f(v0.w) * n0 + bf2f(v1.w) * n1 + bf2f(v2.w) * n2 + bf2f(v3.w) * n3;
        }
        for (; i < n; i++) {
            ushort4 v = *(const ushort4*)&emb[sidx[w][i] * D + lane * 4];
            float nn = snrm[w][i];
            ax += bf2f(v.x) * nn; ay += bf2f(v.y) * nn;
            az += bf2f(v.z) * nn; aw += bf2f(v.w) * nn;
        }
    }
    ushort4 o;
    o.x = f2bf(ax * ndv); o.y = f2bf(ay * ndv);
    o.z = f2bf(az * ndv); o.w = f2bf(aw * ndv);
    *(ushort4*)&agg[dd * D + lane * 4] = o;
}

// MFMA bf16 GEMM, both directions: H = relu(Agg @ W + b), fused Wp row-dot.
// One wave per 16-row M-tile, covering all 256 cols (16 accumulators).
__global__ __launch_bounds__(256) void k_gemm2(
        const unsigned short* __restrict__ aggC, const unsigned short* __restrict__ aggG,
        const unsigned short* __restrict__ wt1, const unsigned short* __restrict__ wt2,
        const float* __restrict__ b_g2c, const float* __restrict__ b_c2g,
        const float* __restrict__ Wp,
        float* __restrict__ hC, float* __restrict__ hG,
        float* __restrict__ sg, float* __restrict__ sc) {
    const int CT = (N_CELL + 15) / 16;   // 53
    const int GT = (N_GENE + 15) / 16;   // 298
    int wid = blockIdx.x * 4 + (threadIdx.x >> 6);
    if (wid >= CT + GT) return;
    bool isCell = wid < CT;
    int tile = isCell ? wid : wid - CT;
    int m0 = tile * 16;
    int M = isCell ? N_CELL : N_GENE;
    const unsigned short* A  = isCell ? aggC : aggG;
    const unsigned short* Wt = isCell ? wt1 : wt2;
    const float* bias = isCell ? b_g2c : b_c2g;
    const float* wp   = isCell ? Wp + D : Wp;   // cells use Wp[256:512]
    float* H  = isCell ? hC : hG;
    float* sv = isCell ? sc : sg;

    int lane = threadIdx.x & 63;
    int l15 = lane & 15, quad = lane >> 4;
    int arow = m0 + l15;
    if (arow >= M) arow = M - 1;              // clamp; OOB rows masked at store
    f32x4 acc[16];
    #pragma unroll
    for (int t = 0; t < 16; t++) acc[t] = (f32x4){0.f, 0.f, 0.f, 0.f};
    #pragma unroll
    for (int k0 = 0; k0 < D; k0 += 32) {
        short8 a = *(const short8*)&A[arow * D + k0 + quad * 8];
        #pragma unroll
        for (int t = 0; t < 16; t++) {
            short8 b = *(const short8*)&Wt[(t * 16 + l15) * D + k0 + quad * 8];
            acc[t] = __builtin_amdgcn_mfma_f32_16x16x32_bf16(a, b, acc[t], 0, 0, 0);
        }
    }
    // epilogue: bias + relu + store + per-row Wp partial dot
    float dot[4] = {0.f, 0.f, 0.f, 0.f};
    #pragma unroll
    for (int t = 0; t < 16; t++) {
        int col = t * 16 + l15;
        float bv = bias[col], wv = wp[col];
        #pragma unroll
        for (int r = 0; r < 4; r++) {
            int row = m0 + quad * 4 + r;
            float h = fmaxf(acc[t][r] + bv, 0.f);
            if (row < M) H[row * D + col] = h;
            dot[r] += h * wv;
        }
    }
    // reduce dots across the 16 lanes of this quad -> complete 256-col dot
    #pragma unroll
    for (int off = 1; off < 16; off <<= 1) {
        #pragma unroll
        for (int r = 0; r < 4; r++) dot[r] += __shfl_xor(dot[r], off);
    }
    if (l15 == 0) {
        #pragma unroll
        for (int r = 0; r < 4; r++) {
            int row = m0 + quad * 4 + r;
            if (row < M) sv[row] = dot[r];
        }
    }
}

__global__ void k_score(const int* __restrict__ dsrc, const int* __restrict__ ddst,
                        const float* __restrict__ sg, const float* __restrict__ sc,
                        const float* __restrict__ bp, float* __restrict__ out) {
    int i = blockIdx.x * blockDim.x + threadIdx.x;
    if (i < NEDGE) out[i] = sg[dsrc[i]] + sc[ddst[i]] + bp[0];
}

extern "C" void kernel_launch(void* const* d_in, const int* in_sizes, int n_in,
                              void* d_out, int out_size, void* d_ws, size_t ws_size,
                              hipStream_t stream) {
    const float* gene_emb = (const float*)d_in[0];
    const float* cell_emb = (const float*)d_in[1];
    const float* W_g2c    = (const float*)d_in[2];
    const float* b_g2c    = (const float*)d_in[3];
    const float* W_c2g    = (const float*)d_in[4];
    const float* b_c2g    = (const float*)d_in[5];
    const float* Wp       = (const float*)d_in[6];
    const float* bp       = (const float*)d_in[7];
    const int* g2c_src = (const int*)d_in[8];
    const int* g2c_dst = (const int*)d_in[9];
    const int* c2g_src = (const int*)d_in[10];
    const int* c2g_dst = (const int*)d_in[11];
    const int* dec_src = (const int*)d_in[12];
    const int* dec_dst = (const int*)d_in[13];

    int*   wsi = (int*)d_ws;
    float* wsf = (float*)d_ws;
    unsigned short* gene_bf = (unsigned short*)(wsi + A_GENE_BF);
    unsigned short* cell_bf = (unsigned short*)(wsi + A_CELL_BF);
    unsigned short* wt1     = (unsigned short*)(wsi + A_WT1_BF);
    unsigned short* wt2     = (unsigned short*)(wsi + A_WT2_BF);
    unsigned short* aggC    = (unsigned short*)(wsi + A_AGGC_BF);
    unsigned short* aggG    = (unsigned short*)(wsi + A_AGGG_BF);

    float* out = (float*)d_out;
    float* out_score = out;                      // [200000]
    float* out_hgene = out + NEDGE;              // [4762*256]
    float* out_hcell = out + NEDGE + N_GENE * D; // [847*256]

    // 1. bf16 conversions + W transposes
    {
        const int total = N_GENE * D + N_CELL * D + 2 * D * D;
        k_cvt<<<(total + 255) / 256, 256, 0, stream>>>(gene_emb, cell_emb, W_g2c, W_c2g,
                                                       gene_bf, cell_bf, wt1, wt2);
    }
    // 2. per-block partial histograms
    k_hist_part<<<NPART, 1024, 0, stream>>>(g2c_src, g2c_dst, c2g_src, c2g_dst,
                                            wsi + A_PART);
    // 3. reduce partials -> deg, nrm; partial := per-block exclusive base ranks
    k_hist_reduce<<<(NBINS + 255) / 256, 256, 0, stream>>>(wsi + A_PART, wsi + A_DEG,
                                                           wsf + A_NRM);
    // 4. CSR offsets for both dst spaces
    k_scan2<<<2, 1024, 0, stream>>>(wsi + A_DEG + S_C_IN, wsi + A_OFFS_C,
                                    wsi + A_DEG + S_G_IN, wsi + A_OFFS_G);
    // 5. deterministic counting sort, both directions
    {
        dim3 grid(NPART, 2);
        k_scatter2<<<grid, 1024, 0, stream>>>(g2c_src, g2c_dst, c2g_src, c2g_dst,
                                              wsi + A_PART, wsi + A_OFFS_C,
                                              wsi + A_OFFS_G, wsi + A_SORT_C,
                                              wsi + A_SORT_G);
    }
    // 6. aggregate both directions (bf16 gathers, bf16 agg out)
    k_agg2<<<(N_CELL + N_GENE + 3) / 4, 256, 0, stream>>>(
        gene_bf, cell_bf, wsi + A_SORT_C, wsi + A_SORT_G,
        wsi + A_OFFS_C, wsi + A_OFFS_G, wsf + A_NRM, aggC, aggG);
    // 7. MFMA GEMMs + bias + relu + fused Wp row-dots
    {
        const int CT = (N_CELL + 15) / 16, GT = (N_GENE + 15) / 16;
        k_gemm2<<<(CT + GT + 3) / 4, 256, 0, stream>>>(aggC, aggG, wt1, wt2,
                                                       b_g2c, b_c2g, Wp,
                                                       out_hcell, out_hgene,
                                                       wsf + A_SG, wsf + A_SC);
    }
    // 8. edge scores
    k_score<<<(NEDGE + 255) / 256, 256, 0, stream>>>(dec_src, dec_dst,
                                                     wsf + A_SG, wsf + A_SC, bp, out_score);
}